// Round 2
// baseline (738.841 us; speedup 1.0000x reference)
//
#include <hip/hip_runtime.h>

typedef unsigned short ushort_t;
typedef unsigned int uint_t;

#define B_SZ 256
#define T_LEN 512
#define Hd 64
#define IND 96
#define G4 256
#define KT 10
#define SYLL_V 10000
#define WORD_V 20000

// workspace layout (in floats)
#define OFF_PS_F 0
#define OFF_PS_B (OFF_PS_F + SYLL_V*G4)            // 2,560,000
#define OFF_PW_F (OFF_PS_B + SYLL_V*G4)            // 5,120,000
#define OFF_PW_B (OFF_PW_F + WORD_V*G4)            // 10,240,000
#define OFF_EM   (OFF_PW_B + WORD_V*G4)            // 15,360,000
#define OFF_OMEGA (OFF_EM + B_SZ*T_LEN*KT)         // 16,670,720
#define OFF_S1   (OFF_OMEGA + B_SZ*64*100)         // 18,309,120
#define OFF_END  (OFF_S1 + B_SZ*64)                // 18,325,504 floats = 73.3 MB
// h_seq (bf16) lives at OFF_END: 256*512*128*2B = 33.55 MB  -> total ws need ~102 MiB

__device__ __forceinline__ float sigm(float x) { return 1.0f / (1.0f + __expf(-x)); }
__device__ __forceinline__ float tanh_f(float x) {
    float e = __expf(2.0f * x);
    return 1.0f - 2.0f / (e + 1.0f);
}
__device__ __forceinline__ ushort_t f2bf(float f) {
    uint_t u = __float_as_uint(f);
    uint_t r = (u + 0x7FFFu + ((u >> 16) & 1u)) >> 16;
    return (ushort_t)r;
}
__device__ __forceinline__ void unpack2(uint_t u, float* o) {
    o[0] = __uint_as_float(u << 16);
    o[1] = __uint_as_float(u & 0xFFFF0000u);
}

// ---------------------------------------------------------------------------
// Kernel 1: per-vocab input-projection tables.
// proj[v][g] = sum_d emb[v][d] * w_ih[g][DOFF+d]
// ---------------------------------------------------------------------------
template <int D, int DOFF>
__global__ __launch_bounds__(128) void proj_kernel(
    const float* __restrict__ emb,
    const float* __restrict__ w_ih_f, const float* __restrict__ w_ih_b,
    float* __restrict__ out_f, float* __restrict__ out_b)
{
    const int dir = blockIdx.y;
    const float* __restrict__ wih = dir ? w_ih_b : w_ih_f;
    float* __restrict__ out = dir ? out_b : out_f;
    const int v0 = blockIdx.x * 8;
    const int tid = threadIdx.x;

    __shared__ float e_lds[8 * D];
    for (int i = tid; i < 8 * D; i += 128) e_lds[i] = emb[v0 * D + i];
    __syncthreads();

    const int g0 = tid * 2, g1 = tid * 2 + 1;
    float w0[D], w1[D];
#pragma unroll
    for (int d = 0; d < D; d++) {
        w0[d] = wih[g0 * IND + DOFF + d];
        w1[d] = wih[g1 * IND + DOFF + d];
    }
    float acc0[8], acc1[8];
#pragma unroll
    for (int r = 0; r < 8; r++) { acc0[r] = 0.f; acc1[r] = 0.f; }
#pragma unroll
    for (int d4 = 0; d4 < D / 4; d4++) {
#pragma unroll
        for (int r = 0; r < 8; r++) {
            float4 e = *(const float4*)&e_lds[r * D + d4 * 4];
            acc0[r] += w0[d4*4+0]*e.x + w0[d4*4+1]*e.y + w0[d4*4+2]*e.z + w0[d4*4+3]*e.w;
            acc1[r] += w1[d4*4+0]*e.x + w1[d4*4+1]*e.y + w1[d4*4+2]*e.z + w1[d4*4+3]*e.w;
        }
    }
#pragma unroll
    for (int r = 0; r < 8; r++) {
        float2 o; o.x = acc0[r]; o.y = acc1[r];
        *(float2*)&out[(v0 + r) * G4 + g0] = o;
    }
}

// ---------------------------------------------------------------------------
// Kernel 2: persistent BiLSTM. One block per (batch, dir). 256 threads = 256
// gates. w_hh row in VGPRs; h broadcast via LDS; xp via proj tables (2 loads).
// ---------------------------------------------------------------------------
__global__ __launch_bounds__(256, 2) void lstm_kernel(
    const int* __restrict__ syll, const int* __restrict__ word,
    const float* __restrict__ w_hh_f, const float* __restrict__ w_hh_b,
    const float* __restrict__ b_ih_f, const float* __restrict__ b_hh_f,
    const float* __restrict__ b_ih_b, const float* __restrict__ b_hh_b,
    const float* __restrict__ ws, ushort_t* __restrict__ h_out)
{
    const int dir = blockIdx.x & 1;
    const int b = blockIdx.x >> 1;
    const int g = threadIdx.x;

    const float* __restrict__ proj_s = ws + (dir ? OFF_PS_B : OFF_PS_F);
    const float* __restrict__ proj_w = ws + (dir ? OFF_PW_B : OFF_PW_F);
    const float* __restrict__ whh_g = (dir ? w_hh_b : w_hh_f) + g * Hd;
    const float bias = dir ? (b_ih_b[g] + b_hh_b[g]) : (b_ih_f[g] + b_hh_f[g]);

    float4 wh[16];
#pragma unroll
    for (int j = 0; j < 16; j++) wh[j] = *(const float4*)&whh_g[j * 4];

    __shared__ float h_sh[Hd];
    __shared__ float gates_sh[G4];
    if (g < Hd) h_sh[g] = 0.0f;
    float c = 0.0f;

    const int* __restrict__ sy = syll + b * T_LEN;
    const int* __restrict__ wo = word + b * T_LEN;
    const int tA = dir ? T_LEN - 1 : 0;
    const int tB = dir ? T_LEN - 2 : 1;
    int si = sy[tA], wi = wo[tA];
    float ps = proj_s[si * G4 + g];
    float pw = proj_w[wi * G4 + g];
    int si1 = sy[tB], wi1 = wo[tB];

    for (int t = 0; t < T_LEN; t++) {
        const int t_act = dir ? (T_LEN - 1 - t) : t;
        // prefetch proj row for t+1, indices for t+2
        float psn = 0.f, pwn = 0.f;
        if (t < T_LEN - 1) { psn = proj_s[si1 * G4 + g]; pwn = proj_w[wi1 * G4 + g]; }
        int si2 = 0, wi2 = 0;
        if (t < T_LEN - 2) {
            int t2 = dir ? (T_LEN - 3 - t) : (t + 2);
            si2 = sy[t2]; wi2 = wo[t2];
        }
        __syncthreads();  // h_sh(t-1) visible
        float a0 = 0.f, a1 = 0.f, a2 = 0.f, a3 = 0.f;
#pragma unroll
        for (int j = 0; j < 4; j++) {
            float4 h0 = *(const float4*)&h_sh[j * 16 + 0];
            float4 h1 = *(const float4*)&h_sh[j * 16 + 4];
            float4 h2 = *(const float4*)&h_sh[j * 16 + 8];
            float4 h3 = *(const float4*)&h_sh[j * 16 + 12];
            float4 q0 = wh[j * 4 + 0], q1 = wh[j * 4 + 1], q2 = wh[j * 4 + 2], q3 = wh[j * 4 + 3];
            a0 += q0.x*h0.x + q0.y*h0.y + q0.z*h0.z + q0.w*h0.w;
            a1 += q1.x*h1.x + q1.y*h1.y + q1.z*h1.z + q1.w*h1.w;
            a2 += q2.x*h2.x + q2.y*h2.y + q2.z*h2.z + q2.w*h2.w;
            a3 += q3.x*h3.x + q3.y*h3.y + q3.z*h3.z + q3.w*h3.w;
        }
        float gate = bias + ps + pw + ((a0 + a1) + (a2 + a3));
        gates_sh[g] = gate;
        __syncthreads();
        if (g < Hd) {
            float iv = sigm(gates_sh[g]);
            float fv = sigm(gates_sh[g + 64]);
            float gv = tanh_f(gates_sh[g + 128]);
            float ov = sigm(gates_sh[g + 192]);
            c = fv * c + iv * gv;
            float h = ov * tanh_f(c);
            h_sh[g] = h;
            h_out[((b * T_LEN + t_act) * 2 + dir) * Hd + g] = f2bf(h);
        }
        ps = psn; pw = pwn; si1 = si2; wi1 = wi2;
    }
}

// ---------------------------------------------------------------------------
// Kernel 3: emissions. One thread per (b,t): em[k] = b_tag[k] + h128 . W_tag[k]
// ---------------------------------------------------------------------------
__global__ __launch_bounds__(256) void emis_kernel(
    const ushort_t* __restrict__ hseq, const float* __restrict__ W_tag,
    const float* __restrict__ b_tag, float* __restrict__ em)
{
    __shared__ float Wt[KT * 128];
    __shared__ float bt[KT];
    const int tid = threadIdx.x;
    for (int i = tid; i < KT * 128; i += 256) Wt[i] = W_tag[i];
    if (tid < KT) bt[tid] = b_tag[tid];
    __syncthreads();

    const int id = blockIdx.x * 256 + tid;  // b*512 + t
    const ushort_t* __restrict__ hr = hseq + (size_t)id * 128;

    float acc[KT];
#pragma unroll
    for (int k = 0; k < KT; k++) acc[k] = bt[k];

#pragma unroll
    for (int ch = 0; ch < 4; ch++) {
        uint4 p0 = *(const uint4*)&hr[ch * 32 + 0];
        uint4 p1 = *(const uint4*)&hr[ch * 32 + 8];
        uint4 p2 = *(const uint4*)&hr[ch * 32 + 16];
        uint4 p3 = *(const uint4*)&hr[ch * 32 + 24];
        float hv[32];
        unpack2(p0.x, hv + 0);  unpack2(p0.y, hv + 2);  unpack2(p0.z, hv + 4);  unpack2(p0.w, hv + 6);
        unpack2(p1.x, hv + 8);  unpack2(p1.y, hv + 10); unpack2(p1.z, hv + 12); unpack2(p1.w, hv + 14);
        unpack2(p2.x, hv + 16); unpack2(p2.y, hv + 18); unpack2(p2.z, hv + 20); unpack2(p2.w, hv + 22);
        unpack2(p3.x, hv + 24); unpack2(p3.y, hv + 26); unpack2(p3.z, hv + 28); unpack2(p3.w, hv + 30);
#pragma unroll
        for (int k = 0; k < KT; k++) {
#pragma unroll
            for (int q = 0; q < 8; q++) {
                float4 w = *(const float4*)&Wt[k * 128 + ch * 32 + q * 4];
                acc[k] += w.x*hv[q*4] + w.y*hv[q*4+1] + w.z*hv[q*4+2] + w.w*hv[q*4+3];
            }
        }
    }
#pragma unroll
    for (int k = 0; k < KT; k++) em[(size_t)id * KT + k] = acc[k];
}

// ---------------------------------------------------------------------------
// Kernel 4: CRF stage 1 — chunk products of transition matrices in exp-space.
// Task (b,c): product of M_t for t in chunk, M_t[j][k] = exp(trans[j][k]) * exp(em[t][k]-mx)
// ---------------------------------------------------------------------------
__global__ __launch_bounds__(256) void crf_stage1(
    const float* __restrict__ em, const float* __restrict__ trans,
    float* __restrict__ Omega, float* __restrict__ S1)
{
    __shared__ float etT[KT * 12];  // transposed exp(trans): etT[k][j]
    const int tid = threadIdx.x;
    if (tid < KT * 12) etT[tid] = 0.f;
    __syncthreads();
    if (tid < 100) { int j = tid / 10, k = tid % 10; etT[k * 12 + j] = __expf(trans[tid]); }
    __syncthreads();

    const int id = blockIdx.x * 256 + tid;  // b*64 + c
    const int b = id >> 6, c = id & 63;
    const int t0 = (c == 0) ? 1 : c * 8;
    const int nt = (c == 0) ? 7 : 8;

    float run[10][10];
    float s = 0.f;

    float ecur[10];
    {
        const float* r = em + (size_t)(b * T_LEN + t0) * KT;
#pragma unroll
        for (int k = 0; k < 10; k++) ecur[k] = r[k];
    }
    // leaf t0
    {
        float mx = ecur[0];
#pragma unroll
        for (int k = 1; k < 10; k++) mx = fmaxf(mx, ecur[k]);
        s += mx;
        float ee[10];
#pragma unroll
        for (int k = 0; k < 10; k++) ee[k] = __expf(ecur[k] - mx);
#pragma unroll
        for (int j = 0; j < 10; j++)
#pragma unroll
            for (int k = 0; k < 10; k++) run[j][k] = etT[k * 12 + j] * ee[k];
    }
    float enx[10];
    if (nt > 1) {
        const float* r = em + (size_t)(b * T_LEN + t0 + 1) * KT;
#pragma unroll
        for (int k = 0; k < 10; k++) enx[k] = r[k];
    }
    for (int li = 1; li < nt; li++) {
        float mx = enx[0];
#pragma unroll
        for (int k = 1; k < 10; k++) mx = fmaxf(mx, enx[k]);
        s += mx;
        float ee[10];
#pragma unroll
        for (int k = 0; k < 10; k++) ee[k] = __expf(enx[k] - mx);
        // prefetch next leaf's emissions
        if (li + 1 < nt) {
            const float* r = em + (size_t)(b * T_LEN + t0 + li + 1) * KT;
#pragma unroll
            for (int k = 0; k < 10; k++) enx[k] = r[k];
        }
        // run = (run @ et) * col-scale ee   (row-local, no second full buffer)
#pragma unroll
        for (int i = 0; i < 10; i++) {
            float out[10];
#pragma unroll
            for (int k = 0; k < 10; k++) {
                float sum = 0.f;
#pragma unroll
                for (int j = 0; j < 10; j++) sum += run[i][j] * etT[k * 12 + j];
                out[k] = sum * ee[k];
            }
#pragma unroll
            for (int k = 0; k < 10; k++) run[i][k] = out[k];
        }
    }
    // normalize
    float m = run[0][0];
#pragma unroll
    for (int i = 0; i < 10; i++)
#pragma unroll
        for (int k = 0; k < 10; k++) m = fmaxf(m, run[i][k]);
    float inv = 1.0f / m;
    s += __logf(m);
#pragma unroll
    for (int i = 0; i < 10; i++)
#pragma unroll
        for (int k = 0; k < 10; k++) Omega[(size_t)id * 100 + i * 10 + k] = run[i][k] * inv;
    S1[id] = s;
}

// ---------------------------------------------------------------------------
// Kernel 5: CRF stage 2 — per-batch tree reduction of 64 chunk matrices
// WITH per-level max-renormalization (fp32 overflow fix), then den, num,
// and the final -mean(llh) accumulation.
// ---------------------------------------------------------------------------
__global__ __launch_bounds__(256) void crf_stage2(
    const float* __restrict__ Omega, const float* __restrict__ S1,
    const float* __restrict__ em, const int* __restrict__ tags,
    const float* __restrict__ start_t, const float* __restrict__ end_t,
    const float* __restrict__ trans, float* __restrict__ out)
{
    const int b = blockIdx.x;
    const int tid = threadIdx.x;
    __shared__ float bufA[64 * 120];
    __shared__ float bufB[32 * 120];
    __shared__ float sh_red[4];
    __shared__ float sh_s;
    __shared__ float scl_sh[32];   // 1/max per product matrix at current level
    __shared__ float lg_sh[32];    // log(max) per product matrix
    __shared__ float lg_acc_sh;    // accumulated log-scales across levels

    for (int idx = tid; idx < 6400; idx += 256) {
        int c = idx / 100, e = idx % 100;
        bufA[c * 120 + (e / 10) * 12 + (e % 10)] = Omega[(size_t)(b * 64 + c) * 100 + e];
    }
    if (tid < 64) {
        float v = S1[b * 64 + tid];
        for (int off = 32; off; off >>= 1) v += __shfl_down(v, off);
        if (tid == 0) sh_s = v;
    }
    if (tid == 0) lg_acc_sh = 0.f;
    __syncthreads();

    float* src = bufA;
    float* dst = bufB;
    for (int n = 32; n >= 1; n >>= 1) {
        for (int idx = tid; idx < n * 100; idx += 256) {
            int p = idx / 100, e = idx % 100, i = e / 10, k = e % 10;
            const float* A = src + (2 * p) * 120;
            const float* Bm = src + (2 * p + 1) * 120;
            float sum = 0.f;
#pragma unroll
            for (int j = 0; j < 10; j++) sum += A[i * 12 + j] * Bm[j * 12 + k];
            dst[p * 120 + i * 12 + k] = sum;
        }
        __syncthreads();
        // per-matrix max-renormalization: inputs at next level stay <= 1,
        // so products are bounded by 10 — no fp32 overflow across levels.
        if (tid < n) {
            const float* M = dst + tid * 120;
            float mx = 0.f;
            for (int i = 0; i < 10; i++)
                for (int k = 0; k < 10; k++) mx = fmaxf(mx, M[i * 12 + k]);
            scl_sh[tid] = 1.0f / mx;
            lg_sh[tid] = __logf(mx);
        }
        __syncthreads();
        if (tid == 0) {
            float s = 0.f;
            for (int p = 0; p < n; p++) s += lg_sh[p];
            lg_acc_sh += s;
        }
        for (int idx = tid; idx < n * 100; idx += 256) {
            int p = idx / 100, e = idx % 100;
            dst[p * 120 + (e / 10) * 12 + (e % 10)] *= scl_sh[p];
        }
        __syncthreads();
        float* t_ = src; src = dst; dst = t_;
    }
    // final (max-normalized) product matrix in src[0..119]; scales in lg_acc_sh

    float den = 0.f;
    if (tid < 64) {
        float val = 0.f;
        float mx0 = 0.f;
        if (tid < 10) {
            mx0 = -1e30f;
            for (int j = 0; j < 10; j++) mx0 = fmaxf(mx0, start_t[j] + em[(size_t)(b * T_LEN) * KT + j]);
            for (int j = 0; j < 10; j++) {
                float v0 = __expf(start_t[j] + em[(size_t)(b * T_LEN) * KT + j] - mx0);
                val += v0 * src[j * 12 + tid];
            }
            val *= __expf(end_t[tid]);
        }
        for (int off = 8; off; off >>= 1) val += __shfl_down(val, off);
        if (tid == 0) den = __logf(val) + mx0 + sh_s + lg_acc_sh;
    }

    // numerator
    float part = 0.f;
    const int* __restrict__ tg = tags + b * T_LEN;
    for (int t = tid; t < T_LEN; t += 256) {
        int cur = tg[t];
        if (t == 0) part += start_t[cur] + em[(size_t)(b * T_LEN) * KT + cur];
        else part += trans[tg[t - 1] * KT + cur] + em[(size_t)(b * T_LEN + t) * KT + cur];
        if (t == T_LEN - 1) part += end_t[cur];
    }
    for (int off = 32; off; off >>= 1) part += __shfl_down(part, off);
    if ((tid & 63) == 0) sh_red[tid >> 6] = part;
    __syncthreads();
    if (tid == 0) {
        float num = sh_red[0] + sh_red[1] + sh_red[2] + sh_red[3];
        float llh = num - den;
        atomicAdd(out, llh * (-1.0f / 256.0f));
    }
}

// ---------------------------------------------------------------------------
extern "C" void kernel_launch(void* const* d_in, const int* in_sizes, int n_in,
                              void* d_out, int out_size, void* d_ws, size_t ws_size,
                              hipStream_t stream) {
    const int* syll      = (const int*)d_in[0];
    const int* word      = (const int*)d_in[1];
    const int* tags      = (const int*)d_in[2];
    // d_in[3] = mask: all ones for this problem; unused.
    const float* syll_emb = (const float*)d_in[4];
    const float* word_emb = (const float*)d_in[5];
    const float* w_ih_f  = (const float*)d_in[6];
    const float* w_hh_f  = (const float*)d_in[7];
    const float* b_ih_f  = (const float*)d_in[8];
    const float* b_hh_f  = (const float*)d_in[9];
    const float* w_ih_b  = (const float*)d_in[10];
    const float* w_hh_b  = (const float*)d_in[11];
    const float* b_ih_b  = (const float*)d_in[12];
    const float* b_hh_b  = (const float*)d_in[13];
    const float* W_tag   = (const float*)d_in[14];
    const float* b_tag   = (const float*)d_in[15];
    const float* crf_start = (const float*)d_in[16];
    const float* crf_end   = (const float*)d_in[17];
    const float* crf_trans = (const float*)d_in[18];

    float* out = (float*)d_out;
    float* ws = (float*)d_ws;
    ushort_t* hseq = (ushort_t*)(ws + OFF_END);

    hipMemsetAsync(d_out, 0, sizeof(float), stream);

    proj_kernel<64, 0><<<dim3(SYLL_V / 8, 2), 128, 0, stream>>>(
        syll_emb, w_ih_f, w_ih_b, ws + OFF_PS_F, ws + OFF_PS_B);
    proj_kernel<32, 64><<<dim3(WORD_V / 8, 2), 128, 0, stream>>>(
        word_emb, w_ih_f, w_ih_b, ws + OFF_PW_F, ws + OFF_PW_B);

    lstm_kernel<<<B_SZ * 2, 256, 0, stream>>>(
        syll, word, w_hh_f, w_hh_b, b_ih_f, b_hh_f, b_ih_b, b_hh_b, ws, hseq);

    emis_kernel<<<B_SZ * T_LEN / 256, 256, 0, stream>>>(hseq, W_tag, b_tag, ws + OFF_EM);

    crf_stage1<<<64, 256, 0, stream>>>(ws + OFF_EM, crf_trans, ws + OFF_OMEGA, ws + OFF_S1);

    crf_stage2<<<B_SZ, 256, 0, stream>>>(
        ws + OFF_OMEGA, ws + OFF_S1, ws + OFF_EM, tags, crf_start, crf_end, crf_trans, out);
}

// Round 3
// 698.958 us; speedup vs baseline: 1.0571x; 1.0571x over previous
//
#include <hip/hip_runtime.h>

typedef unsigned short ushort_t;
typedef unsigned int uint_t;

#define B_SZ 256
#define T_LEN 512
#define Hd 64
#define IND 96
#define G4 256
#define KT 10
#define SYLL_V 10000
#define WORD_V 20000

// workspace layout (in floats)
#define OFF_PS_F 0
#define OFF_PS_B (OFF_PS_F + SYLL_V*G4)            // 2,560,000
#define OFF_PW_F (OFF_PS_B + SYLL_V*G4)            // 5,120,000
#define OFF_PW_B (OFF_PW_F + WORD_V*G4)            // 10,240,000
#define OFF_EM   (OFF_PW_B + WORD_V*G4)            // 15,360,000
#define OFF_OMEGA (OFF_EM + B_SZ*T_LEN*KT)         // 16,670,720
#define OFF_S1   (OFF_OMEGA + B_SZ*64*100)         // 18,309,120
#define OFF_END  (OFF_S1 + B_SZ*64)                // 18,325,504 floats = 73.3 MB
// h_seq (bf16) lives at OFF_END: 256*512*128*2B = 33.55 MB  -> total ws need ~102 MiB

__device__ __forceinline__ float sigm(float x) { return 1.0f / (1.0f + __expf(-x)); }
__device__ __forceinline__ float tanh_f(float x) {
    float e = __expf(2.0f * x);
    return 1.0f - 2.0f / (e + 1.0f);
}
__device__ __forceinline__ ushort_t f2bf(float f) {
    uint_t u = __float_as_uint(f);
    uint_t r = (u + 0x7FFFu + ((u >> 16) & 1u)) >> 16;
    return (ushort_t)r;
}
__device__ __forceinline__ void unpack2(uint_t u, float* o) {
    o[0] = __uint_as_float(u << 16);
    o[1] = __uint_as_float(u & 0xFFFF0000u);
}
__device__ __forceinline__ float dot4(float4 a, float4 b) {
    return a.x*b.x + a.y*b.y + a.z*b.z + a.w*b.w;
}

// ---------------------------------------------------------------------------
// Kernel 1: per-vocab input-projection tables (spill-safe rewrite).
// proj[v][g] = sum_d emb[v][d] * w_ih[g][DOFF+d]
// 256 threads = 256 gates; 16 vocab rows per block; weights chunked 16-at-a-time
// (max live: 16 w + 16 acc ~= 50 VGPR, no spill).
// ---------------------------------------------------------------------------
template <int D, int DOFF>
__global__ __launch_bounds__(256) void proj_kernel(
    const float* __restrict__ emb,
    const float* __restrict__ w_ih_f, const float* __restrict__ w_ih_b,
    float* __restrict__ out_f, float* __restrict__ out_b)
{
    const int dir = blockIdx.y;
    const float* __restrict__ wih = dir ? w_ih_b : w_ih_f;
    float* __restrict__ out = dir ? out_b : out_f;
    const int v0 = blockIdx.x * 16;
    const int g = threadIdx.x;

    __shared__ float e_lds[16 * D];
    for (int i = g; i < 16 * D; i += 256) e_lds[i] = emb[v0 * D + i];
    __syncthreads();

    float acc[16];
#pragma unroll
    for (int r = 0; r < 16; r++) acc[r] = 0.f;

#pragma unroll
    for (int dd = 0; dd < D; dd += 16) {
        const float* wp = &wih[g * IND + DOFF + dd];
        float4 wa = *(const float4*)&wp[0];
        float4 wb = *(const float4*)&wp[4];
        float4 wc = *(const float4*)&wp[8];
        float4 wd = *(const float4*)&wp[12];
#pragma unroll
        for (int r = 0; r < 16; r++) {
            const float* ep = &e_lds[r * D + dd];
            float4 e0 = *(const float4*)&ep[0];
            float4 e1 = *(const float4*)&ep[4];
            float4 e2 = *(const float4*)&ep[8];
            float4 e3 = *(const float4*)&ep[12];
            acc[r] += dot4(wa, e0) + dot4(wb, e1) + dot4(wc, e2) + dot4(wd, e3);
        }
    }
#pragma unroll
    for (int r = 0; r < 16; r++) out[(size_t)(v0 + r) * G4 + g] = acc[r];
}

// ---------------------------------------------------------------------------
// Kernel 2: persistent BiLSTM. One block per (batch, dir), 512 threads =
// 2 threads per gate (32-weight half-dot each, shfl_xor combine).
//  - weights: 8 named float4 (32 VGPR) -> no spill (VGPR cap 128 via lb(512,4))
//  - ONE barrier per step: epilogue replicated per wave (c in regs, h in a
//    per-wave LDS copy); gates exchanged via double-buffered LDS in
//    [cell][gate-type] layout so epilogue reads i,f,g,o with one b128.
//  - depth-2 prefetch of random-access proj rows (step < HBM latency now).
// ---------------------------------------------------------------------------
__global__ __launch_bounds__(512, 4) void lstm_kernel(
    const int* __restrict__ syll, const int* __restrict__ word,
    const float* __restrict__ w_hh_f, const float* __restrict__ w_hh_b,
    const float* __restrict__ b_ih_f, const float* __restrict__ b_hh_f,
    const float* __restrict__ b_ih_b, const float* __restrict__ b_hh_b,
    const float* __restrict__ ws, ushort_t* __restrict__ h_out)
{
    const int dir = blockIdx.x & 1;
    const int b = blockIdx.x >> 1;
    const int tid = threadIdx.x;
    const int g = tid >> 1;       // gate 0..255
    const int half = tid & 1;     // which 32-wide half of the dot
    const int w = tid >> 6;       // wave 0..7
    const int j = tid & 63;       // lane = cell index for epilogue

    const float* __restrict__ tab = half ? (ws + (dir ? OFF_PW_B : OFF_PW_F))
                                         : (ws + (dir ? OFF_PS_B : OFF_PS_F));
    const int* __restrict__ ia = half ? (word + b * T_LEN) : (syll + b * T_LEN);
    const float* __restrict__ whh = (dir ? w_hh_b : w_hh_f) + g * Hd + half * 32;
    const float bias = dir ? (b_ih_b[g] + b_hh_b[g]) : (b_ih_f[g] + b_hh_f[g]);

    // 32 weight floats as named float4s — must stay in VGPRs.
    float4 w0 = *(const float4*)&whh[0];
    float4 w1 = *(const float4*)&whh[4];
    float4 w2 = *(const float4*)&whh[8];
    float4 w3 = *(const float4*)&whh[12];
    float4 w4 = *(const float4*)&whh[16];
    float4 w5 = *(const float4*)&whh[20];
    float4 w6 = *(const float4*)&whh[24];
    float4 w7 = *(const float4*)&whh[28];

    __shared__ __align__(16) float h_w[8][64];        // per-wave h copy
    __shared__ __align__(16) float gates_buf[2][256]; // double-buffered, [cell*4+type]

    h_w[w][j] = 0.0f;
    float c = 0.0f;

    const int step = dir ? -1 : 1;
    const int t0 = dir ? T_LEN - 1 : 0;

    float pC = tab[(size_t)ia[t0] * G4 + g];            // for t
    float pN = tab[(size_t)ia[t0 + step] * G4 + g];     // for t+1
    int idx2 = ia[t0 + 2 * step];                       // index for t+2
    int i3 = t0 + 3 * step;
    i3 = max(0, min(T_LEN - 1, i3));

    ushort_t* __restrict__ hp = h_out + ((size_t)(b * T_LEN + t0) * 2 + dir) * Hd + j;
    const int hstep = step * 2 * Hd;

    for (int t = 0; t < T_LEN; t++) {
        // issue prefetch for t+2 (consumed two rotations later)
        float pN2 = tab[(size_t)idx2 * G4 + g];
        idx2 = ia[i3];
        i3 = max(0, min(T_LEN - 1, i3 + step));

        // half-dot: 32 MACs against this wave's private h copy
        const float* hb = &h_w[w][half * 32];
        float4 h0 = *(const float4*)&hb[0];
        float4 h1 = *(const float4*)&hb[4];
        float4 h2 = *(const float4*)&hb[8];
        float4 h3 = *(const float4*)&hb[12];
        float4 h4 = *(const float4*)&hb[16];
        float4 h5 = *(const float4*)&hb[20];
        float4 h6 = *(const float4*)&hb[24];
        float4 h7 = *(const float4*)&hb[28];
        float acc = dot4(w0, h0) + dot4(w1, h1) + dot4(w2, h2) + dot4(w3, h3)
                  + dot4(w4, h4) + dot4(w5, h5) + dot4(w6, h6) + dot4(w7, h7);
        acc += pC;  // half0 carries ps, half1 carries pw
        acc += __shfl_xor(acc, 1, 64);
        float gate = acc + bias;
        if (!half) gates_buf[t & 1][((g & 63) << 2) | (g >> 6)] = gate;
        __syncthreads();

        // epilogue, replicated in every wave: lane j owns cell j
        float4 gv = *(const float4*)&gates_buf[t & 1][j << 2];
        float iv = sigm(gv.x);
        float fv = sigm(gv.y);
        float gg = tanh_f(gv.z);
        float ov = sigm(gv.w);
        c = fv * c + iv * gg;
        float h = ov * tanh_f(c);
        h_w[w][j] = h;                 // own-wave copy; in-order DS, no barrier
        if (tid < 64) *hp = f2bf(h);   // wave 0 stores the global h sequence
        hp += hstep;
        pC = pN; pN = pN2;
    }
}

// ---------------------------------------------------------------------------
// Kernel 3: emissions. One thread per (b,t): em[k] = b_tag[k] + h128 . W_tag[k]
// ---------------------------------------------------------------------------
__global__ __launch_bounds__(256) void emis_kernel(
    const ushort_t* __restrict__ hseq, const float* __restrict__ W_tag,
    const float* __restrict__ b_tag, float* __restrict__ em)
{
    __shared__ float Wt[KT * 128];
    __shared__ float bt[KT];
    const int tid = threadIdx.x;
    for (int i = tid; i < KT * 128; i += 256) Wt[i] = W_tag[i];
    if (tid < KT) bt[tid] = b_tag[tid];
    __syncthreads();

    const int id = blockIdx.x * 256 + tid;  // b*512 + t
    const ushort_t* __restrict__ hr = hseq + (size_t)id * 128;

    float acc[KT];
#pragma unroll
    for (int k = 0; k < KT; k++) acc[k] = bt[k];

#pragma unroll
    for (int ch = 0; ch < 4; ch++) {
        uint4 p0 = *(const uint4*)&hr[ch * 32 + 0];
        uint4 p1 = *(const uint4*)&hr[ch * 32 + 8];
        uint4 p2 = *(const uint4*)&hr[ch * 32 + 16];
        uint4 p3 = *(const uint4*)&hr[ch * 32 + 24];
        float hv[32];
        unpack2(p0.x, hv + 0);  unpack2(p0.y, hv + 2);  unpack2(p0.z, hv + 4);  unpack2(p0.w, hv + 6);
        unpack2(p1.x, hv + 8);  unpack2(p1.y, hv + 10); unpack2(p1.z, hv + 12); unpack2(p1.w, hv + 14);
        unpack2(p2.x, hv + 16); unpack2(p2.y, hv + 18); unpack2(p2.z, hv + 20); unpack2(p2.w, hv + 22);
        unpack2(p3.x, hv + 24); unpack2(p3.y, hv + 26); unpack2(p3.z, hv + 28); unpack2(p3.w, hv + 30);
#pragma unroll
        for (int k = 0; k < KT; k++) {
#pragma unroll
            for (int q = 0; q < 8; q++) {
                float4 wv = *(const float4*)&Wt[k * 128 + ch * 32 + q * 4];
                acc[k] += wv.x*hv[q*4] + wv.y*hv[q*4+1] + wv.z*hv[q*4+2] + wv.w*hv[q*4+3];
            }
        }
    }
#pragma unroll
    for (int k = 0; k < KT; k++) em[(size_t)id * KT + k] = acc[k];
}

// ---------------------------------------------------------------------------
// Kernel 4: CRF stage 1 — chunk products of transition matrices in exp-space.
// ---------------------------------------------------------------------------
__global__ __launch_bounds__(256) void crf_stage1(
    const float* __restrict__ em, const float* __restrict__ trans,
    float* __restrict__ Omega, float* __restrict__ S1)
{
    __shared__ float etT[KT * 12];  // transposed exp(trans): etT[k][j]
    const int tid = threadIdx.x;
    if (tid < KT * 12) etT[tid] = 0.f;
    __syncthreads();
    if (tid < 100) { int jj = tid / 10, k = tid % 10; etT[k * 12 + jj] = __expf(trans[tid]); }
    __syncthreads();

    const int id = blockIdx.x * 256 + tid;  // b*64 + c
    const int b = id >> 6, c = id & 63;
    const int t0 = (c == 0) ? 1 : c * 8;
    const int nt = (c == 0) ? 7 : 8;

    float run[10][10];
    float s = 0.f;

    float ecur[10];
    {
        const float* r = em + (size_t)(b * T_LEN + t0) * KT;
#pragma unroll
        for (int k = 0; k < 10; k++) ecur[k] = r[k];
    }
    {
        float mx = ecur[0];
#pragma unroll
        for (int k = 1; k < 10; k++) mx = fmaxf(mx, ecur[k]);
        s += mx;
        float ee[10];
#pragma unroll
        for (int k = 0; k < 10; k++) ee[k] = __expf(ecur[k] - mx);
#pragma unroll
        for (int jj = 0; jj < 10; jj++)
#pragma unroll
            for (int k = 0; k < 10; k++) run[jj][k] = etT[k * 12 + jj] * ee[k];
    }
    float enx[10];
    if (nt > 1) {
        const float* r = em + (size_t)(b * T_LEN + t0 + 1) * KT;
#pragma unroll
        for (int k = 0; k < 10; k++) enx[k] = r[k];
    }
    for (int li = 1; li < nt; li++) {
        float mx = enx[0];
#pragma unroll
        for (int k = 1; k < 10; k++) mx = fmaxf(mx, enx[k]);
        s += mx;
        float ee[10];
#pragma unroll
        for (int k = 0; k < 10; k++) ee[k] = __expf(enx[k] - mx);
        if (li + 1 < nt) {
            const float* r = em + (size_t)(b * T_LEN + t0 + li + 1) * KT;
#pragma unroll
            for (int k = 0; k < 10; k++) enx[k] = r[k];
        }
#pragma unroll
        for (int i = 0; i < 10; i++) {
            float outp[10];
#pragma unroll
            for (int k = 0; k < 10; k++) {
                float sum = 0.f;
#pragma unroll
                for (int jj = 0; jj < 10; jj++) sum += run[i][jj] * etT[k * 12 + jj];
                outp[k] = sum * ee[k];
            }
#pragma unroll
            for (int k = 0; k < 10; k++) run[i][k] = outp[k];
        }
    }
    float m = run[0][0];
#pragma unroll
    for (int i = 0; i < 10; i++)
#pragma unroll
        for (int k = 0; k < 10; k++) m = fmaxf(m, run[i][k]);
    float inv = 1.0f / m;
    s += __logf(m);
#pragma unroll
    for (int i = 0; i < 10; i++)
#pragma unroll
        for (int k = 0; k < 10; k++) Omega[(size_t)id * 100 + i * 10 + k] = run[i][k] * inv;
    S1[id] = s;
}

// ---------------------------------------------------------------------------
// Kernel 5: CRF stage 2 — per-batch tree reduction with per-level
// max-renormalization, then den, num, and -mean(llh).
// ---------------------------------------------------------------------------
__global__ __launch_bounds__(256) void crf_stage2(
    const float* __restrict__ Omega, const float* __restrict__ S1,
    const float* __restrict__ em, const int* __restrict__ tags,
    const float* __restrict__ start_t, const float* __restrict__ end_t,
    const float* __restrict__ trans, float* __restrict__ out)
{
    const int b = blockIdx.x;
    const int tid = threadIdx.x;
    __shared__ float bufA[64 * 120];
    __shared__ float bufB[32 * 120];
    __shared__ float sh_red[4];
    __shared__ float sh_s;
    __shared__ float scl_sh[32];
    __shared__ float lg_sh[32];
    __shared__ float lg_acc_sh;

    for (int idx = tid; idx < 6400; idx += 256) {
        int c = idx / 100, e = idx % 100;
        bufA[c * 120 + (e / 10) * 12 + (e % 10)] = Omega[(size_t)(b * 64 + c) * 100 + e];
    }
    if (tid < 64) {
        float v = S1[b * 64 + tid];
        for (int off = 32; off; off >>= 1) v += __shfl_down(v, off);
        if (tid == 0) sh_s = v;
    }
    if (tid == 0) lg_acc_sh = 0.f;
    __syncthreads();

    float* src = bufA;
    float* dst = bufB;
    for (int n = 32; n >= 1; n >>= 1) {
        for (int idx = tid; idx < n * 100; idx += 256) {
            int p = idx / 100, e = idx % 100, i = e / 10, k = e % 10;
            const float* A = src + (2 * p) * 120;
            const float* Bm = src + (2 * p + 1) * 120;
            float sum = 0.f;
#pragma unroll
            for (int jj = 0; jj < 10; jj++) sum += A[i * 12 + jj] * Bm[jj * 12 + k];
            dst[p * 120 + i * 12 + k] = sum;
        }
        __syncthreads();
        if (tid < n) {
            const float* M = dst + tid * 120;
            float mx = 0.f;
            for (int i = 0; i < 10; i++)
                for (int k = 0; k < 10; k++) mx = fmaxf(mx, M[i * 12 + k]);
            scl_sh[tid] = 1.0f / mx;
            lg_sh[tid] = __logf(mx);
        }
        __syncthreads();
        if (tid == 0) {
            float s = 0.f;
            for (int p = 0; p < n; p++) s += lg_sh[p];
            lg_acc_sh += s;
        }
        for (int idx = tid; idx < n * 100; idx += 256) {
            int p = idx / 100, e = idx % 100;
            dst[p * 120 + (e / 10) * 12 + (e % 10)] *= scl_sh[p];
        }
        __syncthreads();
        float* t_ = src; src = dst; dst = t_;
    }

    float den = 0.f;
    if (tid < 64) {
        float val = 0.f;
        float mx0 = 0.f;
        if (tid < 10) {
            mx0 = -1e30f;
            for (int jj = 0; jj < 10; jj++) mx0 = fmaxf(mx0, start_t[jj] + em[(size_t)(b * T_LEN) * KT + jj]);
            for (int jj = 0; jj < 10; jj++) {
                float v0 = __expf(start_t[jj] + em[(size_t)(b * T_LEN) * KT + jj] - mx0);
                val += v0 * src[jj * 12 + tid];
            }
            val *= __expf(end_t[tid]);
        }
        for (int off = 8; off; off >>= 1) val += __shfl_down(val, off);
        if (tid == 0) den = __logf(val) + mx0 + sh_s + lg_acc_sh;
    }

    float part = 0.f;
    const int* __restrict__ tg = tags + b * T_LEN;
    for (int t = tid; t < T_LEN; t += 256) {
        int cur = tg[t];
        if (t == 0) part += start_t[cur] + em[(size_t)(b * T_LEN) * KT + cur];
        else part += trans[tg[t - 1] * KT + cur] + em[(size_t)(b * T_LEN + t) * KT + cur];
        if (t == T_LEN - 1) part += end_t[cur];
    }
    for (int off = 32; off; off >>= 1) part += __shfl_down(part, off);
    if ((tid & 63) == 0) sh_red[tid >> 6] = part;
    __syncthreads();
    if (tid == 0) {
        float num = sh_red[0] + sh_red[1] + sh_red[2] + sh_red[3];
        float llh = num - den;
        atomicAdd(out, llh * (-1.0f / 256.0f));
    }
}

// ---------------------------------------------------------------------------
extern "C" void kernel_launch(void* const* d_in, const int* in_sizes, int n_in,
                              void* d_out, int out_size, void* d_ws, size_t ws_size,
                              hipStream_t stream) {
    const int* syll      = (const int*)d_in[0];
    const int* word      = (const int*)d_in[1];
    const int* tags      = (const int*)d_in[2];
    // d_in[3] = mask: all ones for this problem; unused.
    const float* syll_emb = (const float*)d_in[4];
    const float* word_emb = (const float*)d_in[5];
    const float* w_ih_f  = (const float*)d_in[6];
    const float* w_hh_f  = (const float*)d_in[7];
    const float* b_ih_f  = (const float*)d_in[8];
    const float* b_hh_f  = (const float*)d_in[9];
    const float* w_ih_b  = (const float*)d_in[10];
    const float* w_hh_b  = (const float*)d_in[11];
    const float* b_ih_b  = (const float*)d_in[12];
    const float* b_hh_b  = (const float*)d_in[13];
    const float* W_tag   = (const float*)d_in[14];
    const float* b_tag   = (const float*)d_in[15];
    const float* crf_start = (const float*)d_in[16];
    const float* crf_end   = (const float*)d_in[17];
    const float* crf_trans = (const float*)d_in[18];

    float* out = (float*)d_out;
    float* ws = (float*)d_ws;
    ushort_t* hseq = (ushort_t*)(ws + OFF_END);

    hipMemsetAsync(d_out, 0, sizeof(float), stream);

    proj_kernel<64, 0><<<dim3(SYLL_V / 16, 2), 256, 0, stream>>>(
        syll_emb, w_ih_f, w_ih_b, ws + OFF_PS_F, ws + OFF_PS_B);
    proj_kernel<32, 64><<<dim3(WORD_V / 16, 2), 256, 0, stream>>>(
        word_emb, w_ih_f, w_ih_b, ws + OFF_PW_F, ws + OFF_PW_B);

    lstm_kernel<<<B_SZ * 2, 512, 0, stream>>>(
        syll, word, w_hh_f, w_hh_b, b_ih_f, b_hh_f, b_ih_b, b_hh_b, ws, hseq);

    emis_kernel<<<B_SZ * T_LEN / 256, 256, 0, stream>>>(hseq, W_tag, b_tag, ws + OFF_EM);

    crf_stage1<<<64, 256, 0, stream>>>(ws + OFF_EM, crf_trans, ws + OFF_OMEGA, ws + OFF_S1);

    crf_stage2<<<B_SZ, 256, 0, stream>>>(
        ws + OFF_OMEGA, ws + OFF_S1, ws + OFF_EM, tags, crf_start, crf_end, crf_trans, out);
}

// Round 4
// 487.614 us; speedup vs baseline: 1.5152x; 1.4334x over previous
//
#include <hip/hip_runtime.h>

typedef unsigned short ushort_t;
typedef unsigned int uint_t;
typedef __attribute__((ext_vector_type(8))) short short8;
typedef __attribute__((ext_vector_type(4))) float f32x4;

#define B_SZ 256
#define T_LEN 512
#define Hd 64
#define IND 96
#define G4 256
#define KT 10
#define SYLL_V 10000
#define WORD_V 20000

// workspace layout: bf16 proj tables first (ushort offsets), then fp32 arrays
#define U_PS_F 0
#define U_PS_B (SYLL_V*G4)            // 2,560,000 ushorts
#define U_PW_F (2*SYLL_V*G4)          // 5,120,000
#define U_PW_B (2*SYLL_V*G4 + WORD_V*G4)
#define U_TAB_END (2*SYLL_V*G4 + 2*WORD_V*G4)   // 15,360,000 ushorts = 30.72MB
#define F_EM   (U_TAB_END/2)          // float offset 7,680,000
#define F_OMEGA (F_EM + B_SZ*T_LEN*KT)
#define F_S1   (F_OMEGA + B_SZ*64*100)
#define F_END  (F_S1 + B_SZ*64)       // floats; hseq (bf16) follows

__device__ __forceinline__ float sigm(float x) { return 1.0f / (1.0f + __expf(-x)); }
__device__ __forceinline__ float tanh_f(float x) {
    float e = __expf(2.0f * x);
    return 1.0f - 2.0f / (e + 1.0f);
}
__device__ __forceinline__ ushort_t f2bf(float f) {
    uint_t u = __float_as_uint(f);
    uint_t r = (u + 0x7FFFu + ((u >> 16) & 1u)) >> 16;
    return (ushort_t)r;
}
__device__ __forceinline__ float bf2f(ushort_t u) {
    return __uint_as_float(((uint_t)u) << 16);
}
__device__ __forceinline__ void unpack2(uint_t u, float* o) {
    o[0] = __uint_as_float(u << 16);
    o[1] = __uint_as_float(u & 0xFFFF0000u);
}
__device__ __forceinline__ float dot4(float4 a, float4 b) {
    return a.x*b.x + a.y*b.y + a.z*b.z + a.w*b.w;
}

// ---------------------------------------------------------------------------
// Kernel 1: bf16 per-vocab projection tables, column-SWIZZLED for the lstm
// kernel's wave layout: storage col s = w*64 + tau*16 + n  <->  gate
// g = 16w + 64*tau + n. Thread s computes gate g(s), stores at col s.
// ---------------------------------------------------------------------------
template <int D, int DOFF>
__global__ __launch_bounds__(256) void proj_kernel(
    const float* __restrict__ emb,
    const float* __restrict__ w_ih_f, const float* __restrict__ w_ih_b,
    ushort_t* __restrict__ out_f, ushort_t* __restrict__ out_b)
{
    const int dir = blockIdx.y;
    const float* __restrict__ wih = dir ? w_ih_b : w_ih_f;
    ushort_t* __restrict__ out = dir ? out_b : out_f;
    const int v0 = blockIdx.x * 16;
    const int s = threadIdx.x;
    // inverse swizzle: storage col s -> gate g
    const int w_ = s >> 6, l_ = s & 63, tau = l_ >> 4, nn = l_ & 15;
    const int g = 16 * w_ + 64 * tau + nn;

    __shared__ float e_lds[16 * D];
    for (int i = s; i < 16 * D; i += 256) e_lds[i] = emb[v0 * D + i];
    __syncthreads();

    float acc[16];
#pragma unroll
    for (int r = 0; r < 16; r++) acc[r] = 0.f;

#pragma unroll
    for (int dd = 0; dd < D; dd += 16) {
        const float* wp = &wih[g * IND + DOFF + dd];
        float4 wa = *(const float4*)&wp[0];
        float4 wb = *(const float4*)&wp[4];
        float4 wc = *(const float4*)&wp[8];
        float4 wd = *(const float4*)&wp[12];
#pragma unroll
        for (int r = 0; r < 16; r++) {
            const float* ep = &e_lds[r * D + dd];
            float4 e0 = *(const float4*)&ep[0];
            float4 e1 = *(const float4*)&ep[4];
            float4 e2 = *(const float4*)&ep[8];
            float4 e3 = *(const float4*)&ep[12];
            acc[r] += dot4(wa, e0) + dot4(wb, e1) + dot4(wc, e2) + dot4(wd, e3);
        }
    }
#pragma unroll
    for (int r = 0; r < 16; r++) out[(size_t)(v0 + r) * G4 + s] = f2bf(acc[r]);
}

// ---------------------------------------------------------------------------
// Kernel 2: persistent BiLSTM via MFMA. One block per (batch, dir), 256 thr
// = 4 waves. Wave w owns cells 16w..16w+15 and gate tiles {w, w+4, w+8, w+12}
// (i.e. all 4 gate types for its own cells) -> epilogue is in-lane, ONE
// barrier per step. h lives as bf16[64] in LDS (double-buffered).
//   A-frag: h broadcast into all 16 M-rows (rows identical -> robust to
//   k-relabeling; only C col=lane&15 mapping matters, m89-verified).
//   B-frags: W_hh rows as bf16, resident in 32 VGPRs.
// ---------------------------------------------------------------------------
__global__ __launch_bounds__(256, 2) void lstm_kernel(
    const int* __restrict__ syll, const int* __restrict__ word,
    const float* __restrict__ w_hh_f, const float* __restrict__ w_hh_b,
    const float* __restrict__ b_ih_f, const float* __restrict__ b_hh_f,
    const float* __restrict__ b_ih_b, const float* __restrict__ b_hh_b,
    const ushort_t* __restrict__ tab_base, ushort_t* __restrict__ h_out)
{
    const int dir = blockIdx.x & 1;
    const int b = blockIdx.x >> 1;
    const int tid = threadIdx.x;
    const int w = tid >> 6;        // wave 0..3
    const int l = tid & 63;        // lane
    const int quad = l >> 4;       // 0..3
    const int nn = l & 15;

    const ushort_t* __restrict__ tab_s = tab_base + (dir ? U_PS_B : U_PS_F);
    const ushort_t* __restrict__ tab_w = tab_base + (dir ? U_PW_B : U_PW_F);
    const float* __restrict__ whh = dir ? w_hh_b : w_hh_f;

    // this lane's gate for proj/bias purposes (tau = quad)
    const int g = 16 * w + 64 * quad + nn;
    const float bias = dir ? (b_ih_b[g] + b_hh_b[g]) : (b_ih_f[g] + b_hh_f[g]);
    const int col = w * 64 + l;    // swizzled table column == g

    // B-fragments: tile tau in {0..3} covers gates 16w + 64tau + n, K-chunk c
    // frag element j = w_hh[gate(n=lane&15)][c*32 + quad*8 + j], bf16
    short8 bfrag[4][2];
#pragma unroll
    for (int tau = 0; tau < 4; tau++) {
#pragma unroll
        for (int c = 0; c < 2; c++) {
            const float* wp = whh + (size_t)(16 * w + 64 * tau + nn) * Hd + c * 32 + quad * 8;
            float4 x0 = *(const float4*)&wp[0];
            float4 x1 = *(const float4*)&wp[4];
            short8 f;
            f[0] = (short)f2bf(x0.x); f[1] = (short)f2bf(x0.y);
            f[2] = (short)f2bf(x0.z); f[3] = (short)f2bf(x0.w);
            f[4] = (short)f2bf(x1.x); f[5] = (short)f2bf(x1.y);
            f[6] = (short)f2bf(x1.z); f[7] = (short)f2bf(x1.w);
            bfrag[tau][c] = f;
        }
    }

    __shared__ __align__(16) ushort_t h_bf[2][64];   // double-buffered h (bf16)
    if (tid < 64) { h_bf[0][tid] = 0; h_bf[1][tid] = 0; }
    float c_st = 0.0f;    // cell state, lanes 0..15 of each wave own cell 16w+l

    const int* __restrict__ sy = syll + b * T_LEN;
    const int* __restrict__ wo = word + b * T_LEN;
    const int step = dir ? -1 : 1;
    const int t0 = dir ? T_LEN - 1 : 0;

    // proj prefetch pipeline, depth 2
    float psumA = bias + bf2f(tab_s[(size_t)sy[t0] * G4 + col])
                       + bf2f(tab_w[(size_t)wo[t0] * G4 + col]);
    float psumB = bias + bf2f(tab_s[(size_t)sy[t0 + step] * G4 + col])
                       + bf2f(tab_w[(size_t)wo[t0 + step] * G4 + col]);
    int idx2s = sy[t0 + 2 * step], idx2w = wo[t0 + 2 * step];
    int i3 = max(0, min(T_LEN - 1, t0 + 3 * step));

    ushort_t* __restrict__ hp = h_out + ((size_t)(b * T_LEN + t0) * 2 + dir) * Hd + 16 * w + l;
    const int hstep = step * 2 * Hd;

    __syncthreads();

    for (int t = 0; t < T_LEN; t++) {
        // prefetch proj for t+2
        float psumC = bias + bf2f(tab_s[(size_t)idx2s * G4 + col])
                           + bf2f(tab_w[(size_t)idx2w * G4 + col]);
        idx2s = sy[i3]; idx2w = wo[i3];
        i3 = max(0, min(T_LEN - 1, i3 + step));

        // A-frags: all lanes in a quad read the same 8 h values (broadcast)
        short8 a0 = *(const short8*)&h_bf[t & 1][quad * 8];
        short8 a1 = *(const short8*)&h_bf[t & 1][32 + quad * 8];

        f32x4 z = {0.f, 0.f, 0.f, 0.f};
        f32x4 ac0 = __builtin_amdgcn_mfma_f32_16x16x32_bf16(a0, bfrag[0][0], z, 0, 0, 0);
        f32x4 ac1 = __builtin_amdgcn_mfma_f32_16x16x32_bf16(a0, bfrag[1][0], z, 0, 0, 0);
        f32x4 ac2 = __builtin_amdgcn_mfma_f32_16x16x32_bf16(a0, bfrag[2][0], z, 0, 0, 0);
        f32x4 ac3 = __builtin_amdgcn_mfma_f32_16x16x32_bf16(a0, bfrag[3][0], z, 0, 0, 0);
        ac0 = __builtin_amdgcn_mfma_f32_16x16x32_bf16(a1, bfrag[0][1], ac0, 0, 0, 0);
        ac1 = __builtin_amdgcn_mfma_f32_16x16x32_bf16(a1, bfrag[1][1], ac1, 0, 0, 0);
        ac2 = __builtin_amdgcn_mfma_f32_16x16x32_bf16(a1, bfrag[2][1], ac2, 0, 0, 0);
        ac3 = __builtin_amdgcn_mfma_f32_16x16x32_bf16(a1, bfrag[3][1], ac3, 0, 0, 0);

        // bring proj sums for types 1..3 to lanes 0..15 (type 0 is in-lane)
        float p1 = __shfl(psumA, nn + 16);
        float p2 = __shfl(psumA, nn + 32);
        float p3 = __shfl(psumA, nn + 48);

        if (l < 16) {
            // all C rows identical (A rows identical) -> use reg 0
            float gi = ac0[0] + psumA;
            float gf = ac1[0] + p1;
            float gg = ac2[0] + p2;
            float go = ac3[0] + p3;
            float iv = sigm(gi);
            float fv = sigm(gf);
            float gv = tanh_f(gg);
            float ov = sigm(go);
            c_st = fv * c_st + iv * gv;
            float h = ov * tanh_f(c_st);
            ushort_t hb = f2bf(h);
            h_bf[(t + 1) & 1][16 * w + l] = hb;
            *hp = hb;
        }
        hp += hstep;
        psumA = psumB; psumB = psumC;
        __syncthreads();
    }
}

// ---------------------------------------------------------------------------
// Kernel 3: emissions. One thread per (b,t): em[k] = b_tag[k] + h128 . W_tag[k]
// ---------------------------------------------------------------------------
__global__ __launch_bounds__(256) void emis_kernel(
    const ushort_t* __restrict__ hseq, const float* __restrict__ W_tag,
    const float* __restrict__ b_tag, float* __restrict__ em)
{
    __shared__ float Wt[KT * 128];
    __shared__ float bt[KT];
    const int tid = threadIdx.x;
    for (int i = tid; i < KT * 128; i += 256) Wt[i] = W_tag[i];
    if (tid < KT) bt[tid] = b_tag[tid];
    __syncthreads();

    const int id = blockIdx.x * 256 + tid;  // b*512 + t
    const ushort_t* __restrict__ hr = hseq + (size_t)id * 128;

    float acc[KT];
#pragma unroll
    for (int k = 0; k < KT; k++) acc[k] = bt[k];

#pragma unroll
    for (int ch = 0; ch < 4; ch++) {
        uint4 p0 = *(const uint4*)&hr[ch * 32 + 0];
        uint4 p1 = *(const uint4*)&hr[ch * 32 + 8];
        uint4 p2 = *(const uint4*)&hr[ch * 32 + 16];
        uint4 p3 = *(const uint4*)&hr[ch * 32 + 24];
        float hv[32];
        unpack2(p0.x, hv + 0);  unpack2(p0.y, hv + 2);  unpack2(p0.z, hv + 4);  unpack2(p0.w, hv + 6);
        unpack2(p1.x, hv + 8);  unpack2(p1.y, hv + 10); unpack2(p1.z, hv + 12); unpack2(p1.w, hv + 14);
        unpack2(p2.x, hv + 16); unpack2(p2.y, hv + 18); unpack2(p2.z, hv + 20); unpack2(p2.w, hv + 22);
        unpack2(p3.x, hv + 24); unpack2(p3.y, hv + 26); unpack2(p3.z, hv + 28); unpack2(p3.w, hv + 30);
#pragma unroll
        for (int k = 0; k < KT; k++) {
#pragma unroll
            for (int q = 0; q < 8; q++) {
                float4 wv = *(const float4*)&Wt[k * 128 + ch * 32 + q * 4];
                acc[k] += wv.x*hv[q*4] + wv.y*hv[q*4+1] + wv.z*hv[q*4+2] + wv.w*hv[q*4+3];
            }
        }
    }
#pragma unroll
    for (int k = 0; k < KT; k++) em[(size_t)id * KT + k] = acc[k];
}

// ---------------------------------------------------------------------------
// Kernel 4: CRF stage 1 — chunk products of transition matrices in exp-space.
// ---------------------------------------------------------------------------
__global__ __launch_bounds__(256) void crf_stage1(
    const float* __restrict__ em, const float* __restrict__ trans,
    float* __restrict__ Omega, float* __restrict__ S1)
{
    __shared__ float etT[KT * 12];  // transposed exp(trans): etT[k][j]
    const int tid = threadIdx.x;
    if (tid < KT * 12) etT[tid] = 0.f;
    __syncthreads();
    if (tid < 100) { int jj = tid / 10, k = tid % 10; etT[k * 12 + jj] = __expf(trans[tid]); }
    __syncthreads();

    const int id = blockIdx.x * 256 + tid;  // b*64 + c
    const int b = id >> 6, c = id & 63;
    const int t0 = (c == 0) ? 1 : c * 8;
    const int nt = (c == 0) ? 7 : 8;

    float run[10][10];
    float s = 0.f;

    float ecur[10];
    {
        const float* r = em + (size_t)(b * T_LEN + t0) * KT;
#pragma unroll
        for (int k = 0; k < 10; k++) ecur[k] = r[k];
    }
    {
        float mx = ecur[0];
#pragma unroll
        for (int k = 1; k < 10; k++) mx = fmaxf(mx, ecur[k]);
        s += mx;
        float ee[10];
#pragma unroll
        for (int k = 0; k < 10; k++) ee[k] = __expf(ecur[k] - mx);
#pragma unroll
        for (int jj = 0; jj < 10; jj++)
#pragma unroll
            for (int k = 0; k < 10; k++) run[jj][k] = etT[k * 12 + jj] * ee[k];
    }
    float enx[10];
    if (nt > 1) {
        const float* r = em + (size_t)(b * T_LEN + t0 + 1) * KT;
#pragma unroll
        for (int k = 0; k < 10; k++) enx[k] = r[k];
    }
    for (int li = 1; li < nt; li++) {
        float mx = enx[0];
#pragma unroll
        for (int k = 1; k < 10; k++) mx = fmaxf(mx, enx[k]);
        s += mx;
        float ee[10];
#pragma unroll
        for (int k = 0; k < 10; k++) ee[k] = __expf(enx[k] - mx);
        if (li + 1 < nt) {
            const float* r = em + (size_t)(b * T_LEN + t0 + li + 1) * KT;
#pragma unroll
            for (int k = 0; k < 10; k++) enx[k] = r[k];
        }
#pragma unroll
        for (int i = 0; i < 10; i++) {
            float outp[10];
#pragma unroll
            for (int k = 0; k < 10; k++) {
                float sum = 0.f;
#pragma unroll
                for (int jj = 0; jj < 10; jj++) sum += run[i][jj] * etT[k * 12 + jj];
                outp[k] = sum * ee[k];
            }
#pragma unroll
            for (int k = 0; k < 10; k++) run[i][k] = outp[k];
        }
    }
    float m = run[0][0];
#pragma unroll
    for (int i = 0; i < 10; i++)
#pragma unroll
        for (int k = 0; k < 10; k++) m = fmaxf(m, run[i][k]);
    float inv = 1.0f / m;
    s += __logf(m);
#pragma unroll
    for (int i = 0; i < 10; i++)
#pragma unroll
        for (int k = 0; k < 10; k++) Omega[(size_t)id * 100 + i * 10 + k] = run[i][k] * inv;
    S1[id] = s;
}

// ---------------------------------------------------------------------------
// Kernel 5: CRF stage 2 — per-batch tree reduction with per-level
// max-renormalization, then den, num, and -mean(llh).
// ---------------------------------------------------------------------------
__global__ __launch_bounds__(256) void crf_stage2(
    const float* __restrict__ Omega, const float* __restrict__ S1,
    const float* __restrict__ em, const int* __restrict__ tags,
    const float* __restrict__ start_t, const float* __restrict__ end_t,
    const float* __restrict__ trans, float* __restrict__ out)
{
    const int b = blockIdx.x;
    const int tid = threadIdx.x;
    __shared__ float bufA[64 * 120];
    __shared__ float bufB[32 * 120];
    __shared__ float sh_red[4];
    __shared__ float sh_s;
    __shared__ float scl_sh[32];
    __shared__ float lg_sh[32];
    __shared__ float lg_acc_sh;

    for (int idx = tid; idx < 6400; idx += 256) {
        int c = idx / 100, e = idx % 100;
        bufA[c * 120 + (e / 10) * 12 + (e % 10)] = Omega[(size_t)(b * 64 + c) * 100 + e];
    }
    if (tid < 64) {
        float v = S1[b * 64 + tid];
        for (int off = 32; off; off >>= 1) v += __shfl_down(v, off);
        if (tid == 0) sh_s = v;
    }
    if (tid == 0) lg_acc_sh = 0.f;
    __syncthreads();

    float* src = bufA;
    float* dst = bufB;
    for (int n = 32; n >= 1; n >>= 1) {
        for (int idx = tid; idx < n * 100; idx += 256) {
            int p = idx / 100, e = idx % 100, i = e / 10, k = e % 10;
            const float* A = src + (2 * p) * 120;
            const float* Bm = src + (2 * p + 1) * 120;
            float sum = 0.f;
#pragma unroll
            for (int jj = 0; jj < 10; jj++) sum += A[i * 12 + jj] * Bm[jj * 12 + k];
            dst[p * 120 + i * 12 + k] = sum;
        }
        __syncthreads();
        if (tid < n) {
            const float* M = dst + tid * 120;
            float mx = 0.f;
            for (int i = 0; i < 10; i++)
                for (int k = 0; k < 10; k++) mx = fmaxf(mx, M[i * 12 + k]);
            scl_sh[tid] = 1.0f / mx;
            lg_sh[tid] = __logf(mx);
        }
        __syncthreads();
        if (tid == 0) {
            float s = 0.f;
            for (int p = 0; p < n; p++) s += lg_sh[p];
            lg_acc_sh += s;
        }
        for (int idx = tid; idx < n * 100; idx += 256) {
            int p = idx / 100, e = idx % 100;
            dst[p * 120 + (e / 10) * 12 + (e % 10)] *= scl_sh[p];
        }
        __syncthreads();
        float* t_ = src; src = dst; dst = t_;
    }

    float den = 0.f;
    if (tid < 64) {
        float val = 0.f;
        float mx0 = 0.f;
        if (tid < 10) {
            mx0 = -1e30f;
            for (int jj = 0; jj < 10; jj++) mx0 = fmaxf(mx0, start_t[jj] + em[(size_t)(b * T_LEN) * KT + jj]);
            for (int jj = 0; jj < 10; jj++) {
                float v0 = __expf(start_t[jj] + em[(size_t)(b * T_LEN) * KT + jj] - mx0);
                val += v0 * src[jj * 12 + tid];
            }
            val *= __expf(end_t[tid]);
        }
        for (int off = 8; off; off >>= 1) val += __shfl_down(val, off);
        if (tid == 0) den = __logf(val) + mx0 + sh_s + lg_acc_sh;
    }

    float part = 0.f;
    const int* __restrict__ tg = tags + b * T_LEN;
    for (int t = tid; t < T_LEN; t += 256) {
        int cur = tg[t];
        if (t == 0) part += start_t[cur] + em[(size_t)(b * T_LEN) * KT + cur];
        else part += trans[tg[t - 1] * KT + cur] + em[(size_t)(b * T_LEN + t) * KT + cur];
        if (t == T_LEN - 1) part += end_t[cur];
    }
    for (int off = 32; off; off >>= 1) part += __shfl_down(part, off);
    if ((tid & 63) == 0) sh_red[tid >> 6] = part;
    __syncthreads();
    if (tid == 0) {
        float num = sh_red[0] + sh_red[1] + sh_red[2] + sh_red[3];
        float llh = num - den;
        atomicAdd(out, llh * (-1.0f / 256.0f));
    }
}

// ---------------------------------------------------------------------------
extern "C" void kernel_launch(void* const* d_in, const int* in_sizes, int n_in,
                              void* d_out, int out_size, void* d_ws, size_t ws_size,
                              hipStream_t stream) {
    const int* syll      = (const int*)d_in[0];
    const int* word      = (const int*)d_in[1];
    const int* tags      = (const int*)d_in[2];
    // d_in[3] = mask: all ones for this problem; unused.
    const float* syll_emb = (const float*)d_in[4];
    const float* word_emb = (const float*)d_in[5];
    const float* w_ih_f  = (const float*)d_in[6];
    const float* w_hh_f  = (const float*)d_in[7];
    const float* b_ih_f  = (const float*)d_in[8];
    const float* b_hh_f  = (const float*)d_in[9];
    const float* w_ih_b  = (const float*)d_in[10];
    const float* w_hh_b  = (const float*)d_in[11];
    const float* b_ih_b  = (const float*)d_in[12];
    const float* b_hh_b  = (const float*)d_in[13];
    const float* W_tag   = (const float*)d_in[14];
    const float* b_tag   = (const float*)d_in[15];
    const float* crf_start = (const float*)d_in[16];
    const float* crf_end   = (const float*)d_in[17];
    const float* crf_trans = (const float*)d_in[18];

    float* out = (float*)d_out;
    float* ws = (float*)d_ws;
    ushort_t* tab = (ushort_t*)d_ws;
    ushort_t* hseq = (ushort_t*)(ws + F_END);

    hipMemsetAsync(d_out, 0, sizeof(float), stream);

    proj_kernel<64, 0><<<dim3(SYLL_V / 16, 2), 256, 0, stream>>>(
        syll_emb, w_ih_f, w_ih_b, tab + U_PS_F, tab + U_PS_B);
    proj_kernel<32, 64><<<dim3(WORD_V / 16, 2), 256, 0, stream>>>(
        word_emb, w_ih_f, w_ih_b, tab + U_PW_F, tab + U_PW_B);

    lstm_kernel<<<B_SZ * 2, 256, 0, stream>>>(
        syll, word, w_hh_f, w_hh_b, b_ih_f, b_hh_f, b_ih_b, b_hh_b, tab, hseq);

    emis_kernel<<<B_SZ * T_LEN / 256, 256, 0, stream>>>(hseq, W_tag, b_tag, ws + F_EM);

    crf_stage1<<<64, 256, 0, stream>>>(ws + F_EM, crf_trans, ws + F_OMEGA, ws + F_S1);

    crf_stage2<<<B_SZ, 256, 0, stream>>>(
        ws + F_OMEGA, ws + F_S1, ws + F_EM, tags, crf_start, crf_end, crf_trans, out);
}